// Round 5
// baseline (848.047 us; speedup 1.0000x reference)
//
#include <hip/hip_runtime.h>
#include <hip/hip_bf16.h>

#define N_ENT 100000
#define N_USR 50000
#define DIM   64
#define NE    1000000
#define NNZV  1000000
#define NRELM1 31
#define NSEG  (N_ENT + N_USR)          // concat: [heads | user rows]
#define SCAN_B 1024
#define NB    ((NSEG + SCAN_B - 1) / SCAN_B)   // 147

__device__ __forceinline__ float bf2f(unsigned short u) {
    return __uint_as_float(((unsigned int)u) << 16);
}
__device__ __forceinline__ int geti(const int* p, size_t i, int is64) {
    return is64 ? p[2 * i] : p[i];     // int64 little-endian low word
}
__device__ __forceinline__ float getf(const void* p, size_t i, int isf32) {
    return isf32 ? ((const float*)p)[i] : bf2f(((const unsigned short*)p)[i]);
}
__device__ __forceinline__ int clampi(int v, int lo, int hi) {
    return v < lo ? lo : (v > hi ? hi : v);
}

struct f4 { float x, y, z, w; };

// load dims [4t..4t+3] of row `row` of a [*,64] table (fp32 or bf16)
template<bool F32>
__device__ __forceinline__ f4 row4(const void* p, int row, int t) {
    f4 r;
    if (F32) {
        const float4 v = ((const float4*)p)[(size_t)row * 16 + t];
        r.x = v.x; r.y = v.y; r.z = v.z; r.w = v.w;
    } else {
        const ushort4 v = ((const ushort4*)p)[(size_t)row * 16 + t];
        r.x = bf2f(v.x); r.y = bf2f(v.y); r.z = bf2f(v.z); r.w = bf2f(v.w);
    }
    return r;
}

// ---------------- dtype detection (deterministic, capture-safe) ----------------
__global__ void detect_kernel(const int* __restrict__ eidx,
                              const unsigned short* __restrict__ ent,
                              int* __restrict__ flags) {
    int lane = threadIdx.x & 63;
    int odd = eidx[2 * lane + 1];
    unsigned long long nz = __ballot(odd != 0);
    float v0 = fabsf(bf2f(ent[lane]));
    float v1 = fabsf(bf2f(ent[64 + lane]));
    int wild = (int)((v0 > 100.f) || (v0 != 0.f && v0 < 1e-10f)) +
               (int)((v1 > 100.f) || (v1 != 0.f && v1 < 1e-10f));
    #pragma unroll
    for (int off = 32; off >= 1; off >>= 1) wild += __shfl_xor(wild, off, 64);
    if (lane == 0) {
        flags[0] = (nz == 0ULL) ? 1 : 0;   // is64
        flags[1] = (wild >= 16) ? 1 : 0;   // isf32
    }
}

// ---------------- histogram ----------------
__global__ __launch_bounds__(256) void hist_kernel(
    const int* __restrict__ eidx, const int* __restrict__ irow,
    int* __restrict__ cnt, const int* __restrict__ flags)
{
    int t = blockIdx.x * blockDim.x + threadIdx.x;
    int is64 = flags[0];
    if (t < NE) {
        int head = clampi(geti(eidx, t, is64), 0, N_ENT - 1);
        atomicAdd(cnt + head, 1);
    } else if (t < NE + NNZV) {
        int row = clampi(geti(irow, t - NE, is64), 0, N_USR - 1);
        atomicAdd(cnt + N_ENT + row, 1);
    }
}

// ---------------- scan ----------------
__global__ __launch_bounds__(SCAN_B) void scan1_kernel(
    const int* __restrict__ cnt, int* __restrict__ loc, int* __restrict__ btot)
{
    __shared__ int tmp[SCAN_B];
    int i = blockIdx.x * SCAN_B + threadIdx.x;
    int v = (i < NSEG) ? cnt[i] : 0;
    tmp[threadIdx.x] = v;
    __syncthreads();
    for (int off = 1; off < SCAN_B; off <<= 1) {
        int t = (threadIdx.x >= off) ? tmp[threadIdx.x - off] : 0;
        __syncthreads();
        tmp[threadIdx.x] += t;
        __syncthreads();
    }
    if (i < NSEG) loc[i] = tmp[threadIdx.x] - v;
    if (threadIdx.x == SCAN_B - 1) btot[blockIdx.x] = tmp[SCAN_B - 1];
}

__global__ void scan2_kernel(int* __restrict__ btot) {
    __shared__ int t[NB];
    if (threadIdx.x < NB) t[threadIdx.x] = btot[threadIdx.x];
    __syncthreads();
    if (threadIdx.x == 0) {
        int s = 0;
        for (int i = 0; i < NB; ++i) { int x = t[i]; t[i] = s; s += x; }
    }
    __syncthreads();
    if (threadIdx.x < NB) btot[threadIdx.x] = t[threadIdx.x];
}

__global__ __launch_bounds__(256) void offs_kernel(
    const int* __restrict__ loc, const int* __restrict__ btot,
    int* __restrict__ offs, int* __restrict__ cursor)
{
    int i = blockIdx.x * blockDim.x + threadIdx.x;
    if (i >= NSEG) return;
    int o = loc[i] + btot[i >> 10];
    offs[i] = o;
    cursor[i] = o;
}

// ---------------- scatter into CSR slots ----------------
__global__ __launch_bounds__(256) void scatter_kernel(
    const int* __restrict__ eidx, const int* __restrict__ etype,
    const int* __restrict__ irow, const int* __restrict__ icol,
    const void* __restrict__ ival,
    int* __restrict__ cursor,
    unsigned int* __restrict__ csr_e,   // [(tail<<5)|rel]
    uint2* __restrict__ uv,             // {col, val bits}
    const int* __restrict__ flags)
{
    int t = blockIdx.x * blockDim.x + threadIdx.x;
    int is64 = flags[0], isf32 = flags[1];
    if (t < NE) {
        int head = clampi(geti(eidx, t, is64), 0, N_ENT - 1);
        int tail = clampi(geti(eidx, (size_t)NE + t, is64), 0, N_ENT - 1);
        int rel  = clampi(geti(etype, t, is64) - 1, 0, NRELM1 - 1);
        int pos = atomicAdd(cursor + head, 1);
        csr_e[pos] = ((unsigned)tail << 5) | (unsigned)rel;
    } else if (t < NE + NNZV) {
        int n = t - NE;
        int row = clampi(geti(irow, n, is64), 0, N_USR - 1);
        int col = clampi(geti(icol, n, is64), 0, N_ENT - 1);
        int pos = atomicAdd(cursor + N_ENT + row, 1) - NE;
        uv[pos] = make_uint2((unsigned)col, __float_as_uint(getf(ival, n, isf32)));
    }
}

// ---------------- norm2 table: norm2[e][r] = sum_d ent[e][d]^2 * wgt[r][d]^2 ----------------
// one wave per entity, quartered; quarter q computes rels 8q..8q+7
template<bool F32>
__device__ __forceinline__ void norm2_body(
    const void* ent, const float* w2, float* norm2, int h, int lane)
{
    int q = lane >> 4, t = lane & 15;
    f4 e = row4<F32>(ent, h, t);
    float ex = e.x * e.x, ey = e.y * e.y, ez = e.z * e.z, ew = e.w * e.w;
    float keep = 0.f;
    #pragma unroll
    for (int rl = 0; rl < 8; ++rl) {
        int r = 8 * q + rl;
        float p = 0.f;
        if (r < NRELM1) {
            const float4 wv = ((const float4*)w2)[r * 16 + t];
            p = ex * wv.x + ey * wv.y + ez * wv.z + ew * wv.w;
        }
        #pragma unroll
        for (int off = 1; off < 16; off <<= 1) p += __shfl_xor(p, off, 64);
        keep = (t == rl) ? p : keep;
    }
    int r = 8 * q + t;
    if (t < 8 && r < NRELM1) norm2[(size_t)h * 32 + r] = keep;
}

__global__ __launch_bounds__(256) void norm2_kernel(
    const void* __restrict__ ent, const void* __restrict__ wgt,
    float* __restrict__ norm2, const int* __restrict__ flags)
{
    __shared__ float w2[NRELM1 * DIM];
    int isf32 = flags[1];
    for (int i = threadIdx.x; i < NRELM1 * DIM; i += blockDim.x) {
        float v = getf(wgt, i, isf32);
        w2[i] = v * v;
    }
    __syncthreads();
    int h = (blockIdx.x * blockDim.x + threadIdx.x) >> 6;
    int lane = threadIdx.x & 63;
    if (h >= N_ENT) return;
    if (isf32) norm2_body<true>(ent, w2, norm2, h, lane);
    else       norm2_body<false>(ent, w2, norm2, h, lane);
}

// ---------------- entity aggregation: wave per head, 4 edges/iter ----------------
template<bool F32>
__device__ __forceinline__ void agg_body(
    const void* ent, const float* w, const int* offs, const int* cnt,
    const unsigned int* csr_e, const float* norm2, float* ent_out, int h, int lane)
{
    int q = lane >> 4, t = lane & 15;
    int start = offs[h];
    int deg   = cnt[h];
    const float* hn_row = norm2 + (size_t)h * 32;

    float ax = 0.f, ay = 0.f, az = 0.f, aw = 0.f, s = 0.f;
    int rounds = (deg + 3) >> 2;
    for (int i = 0; i < rounds; ++i) {
        int je = 4 * i + q;
        bool ok = je < deg;
        unsigned pk = csr_e[start + (ok ? je : 0)];
        int tail = (int)(pk >> 5);
        int rel  = (int)(pk & 31u);
        float a = hn_row[rel] * norm2[(size_t)tail * 32 + rel];
        float ex = ok ? __expf(fminf(a, 80.f)) : 0.f;   // max-shift cancels in ratio
        f4 tv = row4<F32>(ent, tail, t);
        const float4 rv = *(const float4*)(w + rel * DIM + 4 * t);
        ax += ex * tv.x * rv.x;
        ay += ex * tv.y * rv.y;
        az += ex * tv.z * rv.z;
        aw += ex * tv.w * rv.w;
        s += ex;
    }
    #pragma unroll
    for (int off = 16; off <= 32; off <<= 1) {
        ax += __shfl_xor(ax, off, 64);
        ay += __shfl_xor(ay, off, 64);
        az += __shfl_xor(az, off, 64);
        aw += __shfl_xor(aw, off, 64);
        s  += __shfl_xor(s,  off, 64);
    }
    float inv = (s > 0.f) ? 1.f / s : 0.f;
    if (lane < 16) {
        float4 o; o.x = ax * inv; o.y = ay * inv; o.z = az * inv; o.w = aw * inv;
        ((float4*)ent_out)[(size_t)h * 16 + t] = o;
    }
}

__global__ __launch_bounds__(256) void agg_kernel(
    const void* __restrict__ ent, const void* __restrict__ wgt,
    const int* __restrict__ offs, const int* __restrict__ cnt,
    const unsigned int* __restrict__ csr_e, const float* __restrict__ norm2,
    float* __restrict__ ent_out, const int* __restrict__ flags)
{
    __shared__ float w[NRELM1 * DIM];
    int isf32 = flags[1];
    for (int i = threadIdx.x; i < NRELM1 * DIM; i += blockDim.x)
        w[i] = getf(wgt, i, isf32);
    __syncthreads();
    int h = (blockIdx.x * blockDim.x + threadIdx.x) >> 6;
    int lane = threadIdx.x & 63;
    if (h >= N_ENT) return;
    if (isf32) agg_body<true>(ent, w, offs, cnt, csr_e, norm2, ent_out, h, lane);
    else       agg_body<false>(ent, w, offs, cnt, csr_e, norm2, ent_out, h, lane);
}

// ---------------- user spmm: wave per user, 4 nnz/iter + fused gate ----------------
template<bool F32>
__device__ __forceinline__ void spmm_body(
    const void* ent, const void* usr, const float* w, const int* offs,
    const int* cnt, const uint2* uv, float* usr_out, int u, int lane)
{
    int q = lane >> 4, t = lane & 15;
    int start = offs[N_ENT + u] - NE;
    int deg   = cnt[N_ENT + u];

    float ax = 0.f, ay = 0.f, az = 0.f, aw = 0.f;
    int rounds = (deg + 3) >> 2;
    for (int i = 0; i < rounds; ++i) {
        int je = 4 * i + q;
        bool ok = je < deg;
        uint2 cv = uv[start + (ok ? je : 0)];
        int col = (int)cv.x;
        float v = ok ? __uint_as_float(cv.y) : 0.f;
        f4 c4 = row4<F32>(ent, col, t);
        ax += v * c4.x; ay += v * c4.y; az += v * c4.z; aw += v * c4.w;
    }
    #pragma unroll
    for (int off = 16; off <= 32; off <<= 1) {
        ax += __shfl_xor(ax, off, 64);
        ay += __shfl_xor(ay, off, 64);
        az += __shfl_xor(az, off, 64);
        aw += __shfl_xor(aw, off, 64);
    }

    // gate: out = ua * (1 + softmax(ue @ W^T) @ W)
    f4 ue = row4<F32>(usr, u, t);
    float p[NRELM1];
    float mx = -1e30f;
    #pragma unroll
    for (int r = 0; r < NRELM1; ++r) {
        const float4 wv = *(const float4*)(w + r * DIM + 4 * t);
        float d = ue.x * wv.x + ue.y * wv.y + ue.z * wv.z + ue.w * wv.w;
        #pragma unroll
        for (int off = 1; off < 16; off <<= 1) d += __shfl_xor(d, off, 64);
        p[r] = d;
        mx = fmaxf(mx, d);
    }
    float sum = 0.f;
    #pragma unroll
    for (int r = 0; r < NRELM1; ++r) { p[r] = __expf(p[r] - mx); sum += p[r]; }
    float inv = 1.f / sum;
    float gx = 0.f, gy = 0.f, gz = 0.f, gw = 0.f;
    #pragma unroll
    for (int r = 0; r < NRELM1; ++r) {
        const float4 wv = *(const float4*)(w + r * DIM + 4 * t);
        gx += p[r] * wv.x; gy += p[r] * wv.y; gz += p[r] * wv.z; gw += p[r] * wv.w;
    }
    if (lane < 16) {
        float4 o;
        o.x = ax * (1.f + gx * inv);
        o.y = ay * (1.f + gy * inv);
        o.z = az * (1.f + gz * inv);
        o.w = aw * (1.f + gw * inv);
        ((float4*)usr_out)[(size_t)u * 16 + t] = o;
    }
}

__global__ __launch_bounds__(256) void spmm_kernel(
    const void* __restrict__ ent, const void* __restrict__ usr,
    const void* __restrict__ wgt,
    const int* __restrict__ offs, const int* __restrict__ cnt,
    const uint2* __restrict__ uv, float* __restrict__ usr_out,
    const int* __restrict__ flags)
{
    __shared__ float w[NRELM1 * DIM];
    int isf32 = flags[1];
    for (int i = threadIdx.x; i < NRELM1 * DIM; i += blockDim.x)
        w[i] = getf(wgt, i, isf32);
    __syncthreads();
    int u = (blockIdx.x * blockDim.x + threadIdx.x) >> 6;
    int lane = threadIdx.x & 63;
    if (u >= N_USR) return;
    if (isf32) spmm_body<true>(ent, usr, w, offs, cnt, uv, usr_out, u, lane);
    else       spmm_body<false>(ent, usr, w, offs, cnt, uv, usr_out, u, lane);
}

extern "C" void kernel_launch(void* const* d_in, const int* in_sizes, int n_in,
                              void* d_out, int out_size, void* d_ws, size_t ws_size,
                              hipStream_t stream) {
    const void* ent  = d_in[0];
    const void* usr  = d_in[1];
    const int* eidx  = (const int*)d_in[2];
    const int* etype = (const int*)d_in[3];
    const int* irow  = (const int*)d_in[4];
    const int* icol  = (const int*)d_in[5];
    const void* ival = d_in[6];
    const void* wgt  = d_in[7];

    float* ent_out = (float*)d_out;                   // [N_ENT*DIM] fp32
    float* usr_out = ent_out + (size_t)N_ENT * DIM;   // [N_USR*DIM] fp32

    // workspace layout
    float* norm2 = (float*)d_ws;                           // N_ENT*32 (stride-32 rows)
    unsigned int* csr_e = (unsigned int*)(norm2 + (size_t)N_ENT * 32);  // NE+64
    uint2* uv   = (uint2*)(csr_e + NE + 64);               // NNZV (8B aligned)
    int* cnt    = (int*)(uv + NNZV);                       // NSEG
    int* loc    = cnt + NSEG;                              // NSEG
    int* btot   = loc + NSEG;                              // 256
    int* offs   = btot + 256;                              // NSEG
    int* cursor = offs + NSEG;                             // NSEG
    int* flags  = cursor + NSEG;                           // 2

    detect_kernel<<<1, 64, 0, stream>>>(eidx, (const unsigned short*)ent, flags);
    hipMemsetAsync(cnt, 0, (size_t)NSEG * sizeof(int), stream);

    hist_kernel<<<(NE + NNZV + 255) / 256, 256, 0, stream>>>(eidx, irow, cnt, flags);
    scan1_kernel<<<NB, SCAN_B, 0, stream>>>(cnt, loc, btot);
    scan2_kernel<<<1, 256, 0, stream>>>(btot);
    offs_kernel<<<(NSEG + 255) / 256, 256, 0, stream>>>(loc, btot, offs, cursor);
    scatter_kernel<<<(NE + NNZV + 255) / 256, 256, 0, stream>>>(
        eidx, etype, irow, icol, ival, cursor, csr_e, uv, flags);
    norm2_kernel<<<(N_ENT * DIM) / 256, 256, 0, stream>>>(ent, wgt, norm2, flags);
    agg_kernel<<<(N_ENT * DIM) / 256, 256, 0, stream>>>(
        ent, wgt, offs, cnt, csr_e, norm2, ent_out, flags);
    spmm_kernel<<<(N_USR * DIM) / 256, 256, 0, stream>>>(
        ent, usr, wgt, offs, cnt, uv, usr_out, flags);
}

// Round 6
// 566.079 us; speedup vs baseline: 1.4981x; 1.4981x over previous
//
#include <hip/hip_runtime.h>
#include <hip/hip_bf16.h>

#define N_ENT 100000
#define N_USR 50000
#define DIM   64
#define NE    1000000
#define NNZV  1000000
#define NRELM1 31
#define NSEG  (N_ENT + N_USR)          // concat: [heads | user rows]
#define SCAN_B 1024
#define NB    ((NSEG + SCAN_B - 1) / SCAN_B)   // 147

__device__ __forceinline__ float bf2f(unsigned short u) {
    return __uint_as_float(((unsigned int)u) << 16);
}
__device__ __forceinline__ int geti(const int* p, size_t i, int is64) {
    return is64 ? p[2 * i] : p[i];     // int64 little-endian low word
}
__device__ __forceinline__ float getf(const void* p, size_t i, int isf32) {
    return isf32 ? ((const float*)p)[i] : bf2f(((const unsigned short*)p)[i]);
}
__device__ __forceinline__ int clampi(int v, int lo, int hi) {
    return v < lo ? lo : (v > hi ? hi : v);
}

struct f4 { float x, y, z, w; };

// load dims [4t..4t+3] of row `row` of a [*,64] table (fp32 or bf16)
template<bool F32>
__device__ __forceinline__ f4 row4(const void* p, int row, int t) {
    f4 r;
    if (F32) {
        const float4 v = ((const float4*)p)[(size_t)row * 16 + t];
        r.x = v.x; r.y = v.y; r.z = v.z; r.w = v.w;
    } else {
        const ushort4 v = ((const ushort4*)p)[(size_t)row * 16 + t];
        r.x = bf2f(v.x); r.y = bf2f(v.y); r.z = bf2f(v.z); r.w = bf2f(v.w);
    }
    return r;
}

// ---------------- dtype detection (deterministic, capture-safe) ----------------
__global__ void detect_kernel(const int* __restrict__ eidx,
                              const unsigned short* __restrict__ ent,
                              int* __restrict__ flags) {
    int lane = threadIdx.x & 63;
    int odd = eidx[2 * lane + 1];
    unsigned long long nz = __ballot(odd != 0);
    float v0 = fabsf(bf2f(ent[lane]));
    float v1 = fabsf(bf2f(ent[64 + lane]));
    int wild = (int)((v0 > 100.f) || (v0 != 0.f && v0 < 1e-10f)) +
               (int)((v1 > 100.f) || (v1 != 0.f && v1 < 1e-10f));
    #pragma unroll
    for (int off = 32; off >= 1; off >>= 1) wild += __shfl_xor(wild, off, 64);
    if (lane == 0) {
        flags[0] = (nz == 0ULL) ? 1 : 0;   // is64
        flags[1] = (wild >= 16) ? 1 : 0;   // isf32
    }
}

// ---------------- histogram ----------------
__global__ __launch_bounds__(256) void hist_kernel(
    const int* __restrict__ eidx, const int* __restrict__ irow,
    int* __restrict__ cnt, const int* __restrict__ flags)
{
    int t = blockIdx.x * blockDim.x + threadIdx.x;
    int is64 = flags[0];
    if (t < NE) {
        int head = clampi(geti(eidx, t, is64), 0, N_ENT - 1);
        atomicAdd(cnt + head, 1);
    } else if (t < NE + NNZV) {
        int row = clampi(geti(irow, t - NE, is64), 0, N_USR - 1);
        atomicAdd(cnt + N_ENT + row, 1);
    }
}

// ---------------- scan ----------------
__global__ __launch_bounds__(SCAN_B) void scan1_kernel(
    const int* __restrict__ cnt, int* __restrict__ loc, int* __restrict__ btot)
{
    __shared__ int tmp[SCAN_B];
    int i = blockIdx.x * SCAN_B + threadIdx.x;
    int v = (i < NSEG) ? cnt[i] : 0;
    tmp[threadIdx.x] = v;
    __syncthreads();
    for (int off = 1; off < SCAN_B; off <<= 1) {
        int t = (threadIdx.x >= off) ? tmp[threadIdx.x - off] : 0;
        __syncthreads();
        tmp[threadIdx.x] += t;
        __syncthreads();
    }
    if (i < NSEG) loc[i] = tmp[threadIdx.x] - v;
    if (threadIdx.x == SCAN_B - 1) btot[blockIdx.x] = tmp[SCAN_B - 1];
}

__global__ void scan2_kernel(int* __restrict__ btot) {
    __shared__ int t[NB];
    if (threadIdx.x < NB) t[threadIdx.x] = btot[threadIdx.x];
    __syncthreads();
    if (threadIdx.x == 0) {
        int s = 0;
        for (int i = 0; i < NB; ++i) { int x = t[i]; t[i] = s; s += x; }
    }
    __syncthreads();
    if (threadIdx.x < NB) btot[threadIdx.x] = t[threadIdx.x];
}

__global__ __launch_bounds__(256) void offs_kernel(
    const int* __restrict__ loc, const int* __restrict__ btot,
    int* __restrict__ offs, int* __restrict__ cursor)
{
    int i = blockIdx.x * blockDim.x + threadIdx.x;
    if (i >= NSEG) return;
    int o = loc[i] + btot[i >> 10];
    offs[i] = o;
    cursor[i] = o;
}

// ---------------- scatter into CSR slots ----------------
__global__ __launch_bounds__(256) void scatter_kernel(
    const int* __restrict__ eidx, const int* __restrict__ etype,
    const int* __restrict__ irow, const int* __restrict__ icol,
    const void* __restrict__ ival,
    int* __restrict__ cursor,
    unsigned int* __restrict__ csr_e,   // [(tail<<5)|rel]
    uint2* __restrict__ uv,             // {col, val bits}
    const int* __restrict__ flags)
{
    int t = blockIdx.x * blockDim.x + threadIdx.x;
    int is64 = flags[0], isf32 = flags[1];
    if (t < NE) {
        int head = clampi(geti(eidx, t, is64), 0, N_ENT - 1);
        int tail = clampi(geti(eidx, (size_t)NE + t, is64), 0, N_ENT - 1);
        int rel  = clampi(geti(etype, t, is64) - 1, 0, NRELM1 - 1);
        int pos = atomicAdd(cursor + head, 1);
        csr_e[pos] = ((unsigned)tail << 5) | (unsigned)rel;
    } else if (t < NE + NNZV) {
        int n = t - NE;
        int row = clampi(geti(irow, n, is64), 0, N_USR - 1);
        int col = clampi(geti(icol, n, is64), 0, N_ENT - 1);
        int pos = atomicAdd(cursor + N_ENT + row, 1) - NE;
        uv[pos] = make_uint2((unsigned)col, __float_as_uint(getf(ival, n, isf32)));
    }
}

// ---------------- norm2 table: norm2[e][r] = sum_d ent[e][d]^2 * wgt[r][d]^2 ----------------
template<bool F32>
__device__ __forceinline__ void norm2_body(
    const void* ent, const float* w2, float* norm2, int h, int lane)
{
    int q = lane >> 4, t = lane & 15;
    f4 e = row4<F32>(ent, h, t);
    float ex = e.x * e.x, ey = e.y * e.y, ez = e.z * e.z, ew = e.w * e.w;
    float keep = 0.f;
    #pragma unroll
    for (int rl = 0; rl < 8; ++rl) {
        int r = 8 * q + rl;
        float p = 0.f;
        if (r < NRELM1) {
            const float4 wv = ((const float4*)w2)[r * 16 + t];
            p = ex * wv.x + ey * wv.y + ez * wv.z + ew * wv.w;
        }
        #pragma unroll
        for (int off = 1; off < 16; off <<= 1) p += __shfl_xor(p, off, 64);
        keep = (t == rl) ? p : keep;
    }
    int r = 8 * q + t;
    if (t < 8 && r < NRELM1) norm2[(size_t)h * 32 + r] = keep;
}

__global__ __launch_bounds__(256) void norm2_kernel(
    const void* __restrict__ ent, const void* __restrict__ wgt,
    float* __restrict__ norm2, const int* __restrict__ flags)
{
    __shared__ float w2[NRELM1 * DIM];
    int isf32 = flags[1];
    for (int i = threadIdx.x; i < NRELM1 * DIM; i += blockDim.x) {
        float v = getf(wgt, i, isf32);
        w2[i] = v * v;
    }
    __syncthreads();
    int h = (blockIdx.x * blockDim.x + threadIdx.x) >> 6;
    int lane = threadIdx.x & 63;
    if (h >= N_ENT) return;
    if (isf32) norm2_body<true>(ent, w2, norm2, h, lane);
    else       norm2_body<false>(ent, w2, norm2, h, lane);
}

// ---------------- entity aggregation: wave per head, 4 edges/iter ----------------
template<bool F32>
__device__ __forceinline__ void agg_body(
    const void* ent, const float* w, const int* offs, const int* cnt,
    const unsigned int* csr_e, const float* norm2, float* ent_out, int h, int lane)
{
    int q = lane >> 4, t = lane & 15;
    int start = offs[h];
    int deg   = cnt[h];
    const float* hn_row = norm2 + (size_t)h * 32;

    float ax = 0.f, ay = 0.f, az = 0.f, aw = 0.f, s = 0.f;
    int rounds = (deg + 3) >> 2;
    for (int i = 0; i < rounds; ++i) {
        int je = 4 * i + q;
        bool ok = je < deg;
        unsigned pk = csr_e[start + (ok ? je : 0)];
        int tail = (int)(pk >> 5);
        int rel  = (int)(pk & 31u);
        float a = hn_row[rel] * norm2[(size_t)tail * 32 + rel];
        float ex = ok ? __expf(fminf(a, 80.f)) : 0.f;   // max-shift cancels in ratio
        f4 tv = row4<F32>(ent, tail, t);
        const float4 rv = *(const float4*)(w + rel * DIM + 4 * t);
        ax += ex * tv.x * rv.x;
        ay += ex * tv.y * rv.y;
        az += ex * tv.z * rv.z;
        aw += ex * tv.w * rv.w;
        s += ex;
    }
    #pragma unroll
    for (int off = 16; off <= 32; off <<= 1) {
        ax += __shfl_xor(ax, off, 64);
        ay += __shfl_xor(ay, off, 64);
        az += __shfl_xor(az, off, 64);
        aw += __shfl_xor(aw, off, 64);
        s  += __shfl_xor(s,  off, 64);
    }
    float inv = (s > 0.f) ? 1.f / s : 0.f;
    if (lane < 16) {
        float4 o; o.x = ax * inv; o.y = ay * inv; o.z = az * inv; o.w = aw * inv;
        ((float4*)ent_out)[(size_t)h * 16 + t] = o;
    }
}

__global__ __launch_bounds__(256) void agg_kernel(
    const void* __restrict__ ent, const void* __restrict__ wgt,
    const int* __restrict__ offs, const int* __restrict__ cnt,
    const unsigned int* __restrict__ csr_e, const float* __restrict__ norm2,
    float* __restrict__ ent_out, const int* __restrict__ flags)
{
    __shared__ float w[NRELM1 * DIM];
    int isf32 = flags[1];
    for (int i = threadIdx.x; i < NRELM1 * DIM; i += blockDim.x)
        w[i] = getf(wgt, i, isf32);
    __syncthreads();
    int h = (blockIdx.x * blockDim.x + threadIdx.x) >> 6;
    int lane = threadIdx.x & 63;
    if (h >= N_ENT) return;
    if (isf32) agg_body<true>(ent, w, offs, cnt, csr_e, norm2, ent_out, h, lane);
    else       agg_body<false>(ent, w, offs, cnt, csr_e, norm2, ent_out, h, lane);
}

// ---------------- user spmm: wave per user, 4 nnz/iter (pure, no gate) ----------------
template<bool F32>
__device__ __forceinline__ void spmm_body(
    const void* ent, const int* offs, const int* cnt,
    const uint2* uv, float* usr_out, int u, int lane)
{
    int q = lane >> 4, t = lane & 15;
    int start = offs[N_ENT + u] - NE;
    int deg   = cnt[N_ENT + u];

    float ax = 0.f, ay = 0.f, az = 0.f, aw = 0.f;
    int rounds = (deg + 3) >> 2;
    for (int i = 0; i < rounds; ++i) {
        int je = 4 * i + q;
        bool ok = je < deg;
        uint2 cv = uv[start + (ok ? je : 0)];
        int col = (int)cv.x;
        float v = ok ? __uint_as_float(cv.y) : 0.f;
        f4 c4 = row4<F32>(ent, col, t);
        ax += v * c4.x; ay += v * c4.y; az += v * c4.z; aw += v * c4.w;
    }
    #pragma unroll
    for (int off = 16; off <= 32; off <<= 1) {
        ax += __shfl_xor(ax, off, 64);
        ay += __shfl_xor(ay, off, 64);
        az += __shfl_xor(az, off, 64);
        aw += __shfl_xor(aw, off, 64);
    }
    if (lane < 16) {
        float4 o; o.x = ax; o.y = ay; o.z = az; o.w = aw;
        ((float4*)usr_out)[(size_t)u * 16 + t] = o;
    }
}

__global__ __launch_bounds__(256) void spmm_kernel(
    const void* __restrict__ ent,
    const int* __restrict__ offs, const int* __restrict__ cnt,
    const uint2* __restrict__ uv, float* __restrict__ usr_out,
    const int* __restrict__ flags)
{
    int u = (blockIdx.x * blockDim.x + threadIdx.x) >> 6;
    int lane = threadIdx.x & 63;
    if (u >= N_USR) return;
    if (flags[1]) spmm_body<true>(ent, offs, cnt, uv, usr_out, u, lane);
    else          spmm_body<false>(ent, offs, cnt, uv, usr_out, u, lane);
}

// ---------------- gate: thread-per-user, applied in place on usr_out ----------------
// out = ua * (1 + softmax(ue @ W^T) @ W); W staged in LDS (broadcast reads)
template<bool F32>
__device__ __forceinline__ void gate_body(
    const void* usr, const float* w, float* usr_out, int u)
{
    float p[NRELM1];
    #pragma unroll
    for (int r = 0; r < NRELM1; ++r) p[r] = 0.f;
    #pragma unroll 4
    for (int t = 0; t < 16; ++t) {
        f4 ue = row4<F32>(usr, u, t);
        #pragma unroll
        for (int r = 0; r < NRELM1; ++r) {
            const float4 wv = *(const float4*)(w + r * DIM + 4 * t);
            p[r] += ue.x * wv.x + ue.y * wv.y + ue.z * wv.z + ue.w * wv.w;
        }
    }
    float mx = -1e30f;
    #pragma unroll
    for (int r = 0; r < NRELM1; ++r) mx = fmaxf(mx, p[r]);
    float sum = 0.f;
    #pragma unroll
    for (int r = 0; r < NRELM1; ++r) { p[r] = __expf(p[r] - mx); sum += p[r]; }
    float inv = 1.f / sum;
    #pragma unroll
    for (int r = 0; r < NRELM1; ++r) p[r] *= inv;

    float4* uo = (float4*)usr_out + (size_t)u * 16;
    #pragma unroll 4
    for (int t = 0; t < 16; ++t) {
        float gx = 0.f, gy = 0.f, gz = 0.f, gw = 0.f;
        #pragma unroll
        for (int r = 0; r < NRELM1; ++r) {
            const float4 wv = *(const float4*)(w + r * DIM + 4 * t);
            gx += p[r] * wv.x; gy += p[r] * wv.y; gz += p[r] * wv.z; gw += p[r] * wv.w;
        }
        float4 ua = uo[t];
        ua.x *= (1.f + gx); ua.y *= (1.f + gy); ua.z *= (1.f + gz); ua.w *= (1.f + gw);
        uo[t] = ua;
    }
}

__global__ __launch_bounds__(256) void gate_kernel(
    const void* __restrict__ usr, const void* __restrict__ wgt,
    float* __restrict__ usr_out, const int* __restrict__ flags)
{
    __shared__ float w[NRELM1 * DIM];
    int isf32 = flags[1];
    for (int i = threadIdx.x; i < NRELM1 * DIM; i += blockDim.x)
        w[i] = getf(wgt, i, isf32);
    __syncthreads();
    int u = blockIdx.x * blockDim.x + threadIdx.x;
    if (u >= N_USR) return;
    if (isf32) gate_body<true>(usr, w, usr_out, u);
    else       gate_body<false>(usr, w, usr_out, u);
}

extern "C" void kernel_launch(void* const* d_in, const int* in_sizes, int n_in,
                              void* d_out, int out_size, void* d_ws, size_t ws_size,
                              hipStream_t stream) {
    const void* ent  = d_in[0];
    const void* usr  = d_in[1];
    const int* eidx  = (const int*)d_in[2];
    const int* etype = (const int*)d_in[3];
    const int* irow  = (const int*)d_in[4];
    const int* icol  = (const int*)d_in[5];
    const void* ival = d_in[6];
    const void* wgt  = d_in[7];

    float* ent_out = (float*)d_out;                   // [N_ENT*DIM] fp32
    float* usr_out = ent_out + (size_t)N_ENT * DIM;   // [N_USR*DIM] fp32

    // workspace layout
    float* norm2 = (float*)d_ws;                           // N_ENT*32 (stride-32 rows)
    unsigned int* csr_e = (unsigned int*)(norm2 + (size_t)N_ENT * 32);  // NE+64
    uint2* uv   = (uint2*)(csr_e + NE + 64);               // NNZV (8B aligned)
    int* cnt    = (int*)(uv + NNZV);                       // NSEG
    int* loc    = cnt + NSEG;                              // NSEG
    int* btot   = loc + NSEG;                              // 256
    int* offs   = btot + 256;                              // NSEG
    int* cursor = offs + NSEG;                             // NSEG
    int* flags  = cursor + NSEG;                           // 2

    detect_kernel<<<1, 64, 0, stream>>>(eidx, (const unsigned short*)ent, flags);
    hipMemsetAsync(cnt, 0, (size_t)NSEG * sizeof(int), stream);

    hist_kernel<<<(NE + NNZV + 255) / 256, 256, 0, stream>>>(eidx, irow, cnt, flags);
    scan1_kernel<<<NB, SCAN_B, 0, stream>>>(cnt, loc, btot);
    scan2_kernel<<<1, 256, 0, stream>>>(btot);
    offs_kernel<<<(NSEG + 255) / 256, 256, 0, stream>>>(loc, btot, offs, cursor);
    scatter_kernel<<<(NE + NNZV + 255) / 256, 256, 0, stream>>>(
        eidx, etype, irow, icol, ival, cursor, csr_e, uv, flags);
    norm2_kernel<<<(N_ENT * DIM) / 256, 256, 0, stream>>>(ent, wgt, norm2, flags);
    agg_kernel<<<(N_ENT * DIM) / 256, 256, 0, stream>>>(
        ent, wgt, offs, cnt, csr_e, norm2, ent_out, flags);
    spmm_kernel<<<(N_USR * DIM) / 256, 256, 0, stream>>>(
        ent, offs, cnt, uv, usr_out, flags);
    gate_kernel<<<(N_USR + 255) / 256, 256, 0, stream>>>(usr, wgt, usr_out, flags);
}

// Round 7
// 499.368 us; speedup vs baseline: 1.6982x; 1.1336x over previous
//
#include <hip/hip_runtime.h>
#include <hip/hip_bf16.h>

#define N_ENT 100000
#define N_USR 50000
#define DIM   64
#define NE    1000000
#define NNZV  1000000
#define NRELM1 31
#define NSEG  (N_ENT + N_USR)          // concat: [heads | user rows]
#define SCAN_B 1024
#define NB    ((NSEG + SCAN_B - 1) / SCAN_B)   // 147
#define NXCD  8
#define ENT_PER_XCD (N_ENT / NXCD)     // 12500
#define USR_PER_XCD (N_USR / NXCD)     // 6250

__device__ __forceinline__ float bf2f(unsigned short u) {
    return __uint_as_float(((unsigned int)u) << 16);
}
__device__ __forceinline__ int geti(const int* p, size_t i, int is64) {
    return is64 ? p[2 * i] : p[i];     // int64 little-endian low word
}
__device__ __forceinline__ float getf(const void* p, size_t i, int isf32) {
    return isf32 ? ((const float*)p)[i] : bf2f(((const unsigned short*)p)[i]);
}
__device__ __forceinline__ int clampi(int v, int lo, int hi) {
    return v < lo ? lo : (v > hi ? hi : v);
}

struct f4 { float x, y, z, w; };

// load dims [4t..4t+3] of row `row` of a [*,64] table (fp32 or bf16)
template<bool F32>
__device__ __forceinline__ f4 row4(const void* p, int row, int t) {
    f4 r;
    if (F32) {
        const float4 v = ((const float4*)p)[(size_t)row * 16 + t];
        r.x = v.x; r.y = v.y; r.z = v.z; r.w = v.w;
    } else {
        const ushort4 v = ((const ushort4*)p)[(size_t)row * 16 + t];
        r.x = bf2f(v.x); r.y = bf2f(v.y); r.z = bf2f(v.z); r.w = bf2f(v.w);
    }
    return r;
}

// ---------------- dtype detection (deterministic, capture-safe) ----------------
__global__ void detect_kernel(const int* __restrict__ eidx,
                              const unsigned short* __restrict__ ent,
                              int* __restrict__ flags) {
    int lane = threadIdx.x & 63;
    int odd = eidx[2 * lane + 1];
    unsigned long long nz = __ballot(odd != 0);
    float v0 = fabsf(bf2f(ent[lane]));
    float v1 = fabsf(bf2f(ent[64 + lane]));
    int wild = (int)((v0 > 100.f) || (v0 != 0.f && v0 < 1e-10f)) +
               (int)((v1 > 100.f) || (v1 != 0.f && v1 < 1e-10f));
    #pragma unroll
    for (int off = 32; off >= 1; off >>= 1) wild += __shfl_xor(wild, off, 64);
    if (lane == 0) {
        flags[0] = (nz == 0ULL) ? 1 : 0;   // is64
        flags[1] = (wild >= 16) ? 1 : 0;   // isf32
    }
}

// ---------------- histogram ----------------
__global__ __launch_bounds__(256) void hist_kernel(
    const int* __restrict__ eidx, const int* __restrict__ irow,
    int* __restrict__ cnt, const int* __restrict__ flags)
{
    int t = blockIdx.x * blockDim.x + threadIdx.x;
    int is64 = flags[0];
    if (t < NE) {
        int head = clampi(geti(eidx, t, is64), 0, N_ENT - 1);
        atomicAdd(cnt + head, 1);
    } else if (t < NE + NNZV) {
        int row = clampi(geti(irow, t - NE, is64), 0, N_USR - 1);
        atomicAdd(cnt + N_ENT + row, 1);
    }
}

// ---------------- scan ----------------
__global__ __launch_bounds__(SCAN_B) void scan1_kernel(
    const int* __restrict__ cnt, int* __restrict__ loc, int* __restrict__ btot)
{
    __shared__ int tmp[SCAN_B];
    int i = blockIdx.x * SCAN_B + threadIdx.x;
    int v = (i < NSEG) ? cnt[i] : 0;
    tmp[threadIdx.x] = v;
    __syncthreads();
    for (int off = 1; off < SCAN_B; off <<= 1) {
        int t = (threadIdx.x >= off) ? tmp[threadIdx.x - off] : 0;
        __syncthreads();
        tmp[threadIdx.x] += t;
        __syncthreads();
    }
    if (i < NSEG) loc[i] = tmp[threadIdx.x] - v;
    if (threadIdx.x == SCAN_B - 1) btot[blockIdx.x] = tmp[SCAN_B - 1];
}

__global__ void scan2_kernel(int* __restrict__ btot) {
    __shared__ int t[NB];
    if (threadIdx.x < NB) t[threadIdx.x] = btot[threadIdx.x];
    __syncthreads();
    if (threadIdx.x == 0) {
        int s = 0;
        for (int i = 0; i < NB; ++i) { int x = t[i]; t[i] = s; s += x; }
    }
    __syncthreads();
    if (threadIdx.x < NB) btot[threadIdx.x] = t[threadIdx.x];
}

__global__ __launch_bounds__(256) void offs_kernel(
    const int* __restrict__ loc, const int* __restrict__ btot,
    int* __restrict__ offs, int* __restrict__ cursor)
{
    int i = blockIdx.x * blockDim.x + threadIdx.x;
    if (i >= NSEG) return;
    int o = loc[i] + btot[i >> 10];
    offs[i] = o;
    cursor[i] = o;
}

// ---------------- scatter into CSR slots, XCD-range-filtered ----------------
// block b: item chunk b>>3, destination range b&7. Range r owns heads
// [r*12500,(r+1)*12500) / rows [r*6250,(r+1)*6250). CSR positions are monotone
// in head/row, so each destination cacheline is written by (almost) only one
// range -> one XCD's L2 (blockIdx%8 round-robin heuristic) -> full-line
// write-back instead of 11x partial-line HBM write amplification.
__global__ __launch_bounds__(256) void scatter_kernel(
    const int* __restrict__ eidx, const int* __restrict__ etype,
    const int* __restrict__ irow, const int* __restrict__ icol,
    const void* __restrict__ ival,
    int* __restrict__ cursor,
    unsigned int* __restrict__ csr_e,   // [(tail<<5)|rel]
    uint2* __restrict__ uv,             // {col, val bits}
    const int* __restrict__ flags)
{
    int rng = blockIdx.x & (NXCD - 1);
    int t = (blockIdx.x >> 3) * blockDim.x + threadIdx.x;
    int is64 = flags[0], isf32 = flags[1];
    if (t < NE) {
        int head = clampi(geti(eidx, t, is64), 0, N_ENT - 1);
        if (head / ENT_PER_XCD == rng) {
            int tail = clampi(geti(eidx, (size_t)NE + t, is64), 0, N_ENT - 1);
            int rel  = clampi(geti(etype, t, is64) - 1, 0, NRELM1 - 1);
            int pos = atomicAdd(cursor + head, 1);
            csr_e[pos] = ((unsigned)tail << 5) | (unsigned)rel;
        }
    } else if (t < NE + NNZV) {
        int n = t - NE;
        int row = clampi(geti(irow, n, is64), 0, N_USR - 1);
        if (row / USR_PER_XCD == rng) {
            int col = clampi(geti(icol, n, is64), 0, N_ENT - 1);
            int pos = atomicAdd(cursor + N_ENT + row, 1) - NE;
            uv[pos] = make_uint2((unsigned)col, __float_as_uint(getf(ival, n, isf32)));
        }
    }
}

// ---------------- norm2 table: norm2[e][r] = sum_d ent[e][d]^2 * wgt[r][d]^2 ----------------
template<bool F32>
__device__ __forceinline__ void norm2_body(
    const void* ent, const float* w2, float* norm2, int h, int lane)
{
    int q = lane >> 4, t = lane & 15;
    f4 e = row4<F32>(ent, h, t);
    float ex = e.x * e.x, ey = e.y * e.y, ez = e.z * e.z, ew = e.w * e.w;
    float keep = 0.f;
    #pragma unroll
    for (int rl = 0; rl < 8; ++rl) {
        int r = 8 * q + rl;
        float p = 0.f;
        if (r < NRELM1) {
            const float4 wv = ((const float4*)w2)[r * 16 + t];
            p = ex * wv.x + ey * wv.y + ez * wv.z + ew * wv.w;
        }
        #pragma unroll
        for (int off = 1; off < 16; off <<= 1) p += __shfl_xor(p, off, 64);
        keep = (t == rl) ? p : keep;
    }
    int r = 8 * q + t;
    if (t < 8 && r < NRELM1) norm2[(size_t)h * 32 + r] = keep;
}

__global__ __launch_bounds__(256) void norm2_kernel(
    const void* __restrict__ ent, const void* __restrict__ wgt,
    float* __restrict__ norm2, const int* __restrict__ flags)
{
    __shared__ float w2[NRELM1 * DIM];
    int isf32 = flags[1];
    for (int i = threadIdx.x; i < NRELM1 * DIM; i += blockDim.x) {
        float v = getf(wgt, i, isf32);
        w2[i] = v * v;
    }
    __syncthreads();
    int h = (blockIdx.x * blockDim.x + threadIdx.x) >> 6;
    int lane = threadIdx.x & 63;
    if (h >= N_ENT) return;
    if (isf32) norm2_body<true>(ent, w2, norm2, h, lane);
    else       norm2_body<false>(ent, w2, norm2, h, lane);
}

// ---------------- entity aggregation: wave per head, 4 edges/iter ----------------
template<bool F32>
__device__ __forceinline__ void agg_body(
    const void* ent, const float* w, const int* offs, const int* cnt,
    const unsigned int* csr_e, const float* norm2, float* ent_out, int h, int lane)
{
    int q = lane >> 4, t = lane & 15;
    int start = offs[h];
    int deg   = cnt[h];
    const float* hn_row = norm2 + (size_t)h * 32;

    float ax = 0.f, ay = 0.f, az = 0.f, aw = 0.f, s = 0.f;
    int rounds = (deg + 3) >> 2;
    for (int i = 0; i < rounds; ++i) {
        int je = 4 * i + q;
        bool ok = je < deg;
        unsigned pk = csr_e[start + (ok ? je : 0)];
        int tail = (int)(pk >> 5);
        int rel  = (int)(pk & 31u);
        float a = hn_row[rel] * norm2[(size_t)tail * 32 + rel];
        float ex = ok ? __expf(fminf(a, 80.f)) : 0.f;   // max-shift cancels in ratio
        f4 tv = row4<F32>(ent, tail, t);
        const float4 rv = *(const float4*)(w + rel * DIM + 4 * t);
        ax += ex * tv.x * rv.x;
        ay += ex * tv.y * rv.y;
        az += ex * tv.z * rv.z;
        aw += ex * tv.w * rv.w;
        s += ex;
    }
    #pragma unroll
    for (int off = 16; off <= 32; off <<= 1) {
        ax += __shfl_xor(ax, off, 64);
        ay += __shfl_xor(ay, off, 64);
        az += __shfl_xor(az, off, 64);
        aw += __shfl_xor(aw, off, 64);
        s  += __shfl_xor(s,  off, 64);
    }
    float inv = (s > 0.f) ? 1.f / s : 0.f;
    if (lane < 16) {
        float4 o; o.x = ax * inv; o.y = ay * inv; o.z = az * inv; o.w = aw * inv;
        ((float4*)ent_out)[(size_t)h * 16 + t] = o;
    }
}

__global__ __launch_bounds__(256) void agg_kernel(
    const void* __restrict__ ent, const void* __restrict__ wgt,
    const int* __restrict__ offs, const int* __restrict__ cnt,
    const unsigned int* __restrict__ csr_e, const float* __restrict__ norm2,
    float* __restrict__ ent_out, const int* __restrict__ flags)
{
    __shared__ float w[NRELM1 * DIM];
    int isf32 = flags[1];
    for (int i = threadIdx.x; i < NRELM1 * DIM; i += blockDim.x)
        w[i] = getf(wgt, i, isf32);
    __syncthreads();
    int h = (blockIdx.x * blockDim.x + threadIdx.x) >> 6;
    int lane = threadIdx.x & 63;
    if (h >= N_ENT) return;
    if (isf32) agg_body<true>(ent, w, offs, cnt, csr_e, norm2, ent_out, h, lane);
    else       agg_body<false>(ent, w, offs, cnt, csr_e, norm2, ent_out, h, lane);
}

// ---------------- user spmm: wave per user, 4 nnz/iter (pure, no gate) ----------------
template<bool F32>
__device__ __forceinline__ void spmm_body(
    const void* ent, const int* offs, const int* cnt,
    const uint2* uv, float* usr_out, int u, int lane)
{
    int q = lane >> 4, t = lane & 15;
    int start = offs[N_ENT + u] - NE;
    int deg   = cnt[N_ENT + u];

    float ax = 0.f, ay = 0.f, az = 0.f, aw = 0.f;
    int rounds = (deg + 3) >> 2;
    for (int i = 0; i < rounds; ++i) {
        int je = 4 * i + q;
        bool ok = je < deg;
        uint2 cv = uv[start + (ok ? je : 0)];
        int col = (int)cv.x;
        float v = ok ? __uint_as_float(cv.y) : 0.f;
        f4 c4 = row4<F32>(ent, col, t);
        ax += v * c4.x; ay += v * c4.y; az += v * c4.z; aw += v * c4.w;
    }
    #pragma unroll
    for (int off = 16; off <= 32; off <<= 1) {
        ax += __shfl_xor(ax, off, 64);
        ay += __shfl_xor(ay, off, 64);
        az += __shfl_xor(az, off, 64);
        aw += __shfl_xor(aw, off, 64);
    }
    if (lane < 16) {
        float4 o; o.x = ax; o.y = ay; o.z = az; o.w = aw;
        ((float4*)usr_out)[(size_t)u * 16 + t] = o;
    }
}

__global__ __launch_bounds__(256) void spmm_kernel(
    const void* __restrict__ ent,
    const int* __restrict__ offs, const int* __restrict__ cnt,
    const uint2* __restrict__ uv, float* __restrict__ usr_out,
    const int* __restrict__ flags)
{
    int u = (blockIdx.x * blockDim.x + threadIdx.x) >> 6;
    int lane = threadIdx.x & 63;
    if (u >= N_USR) return;
    if (flags[1]) spmm_body<true>(ent, offs, cnt, uv, usr_out, u, lane);
    else          spmm_body<false>(ent, offs, cnt, uv, usr_out, u, lane);
}

// ---------------- gate: thread-per-user, applied in place on usr_out ----------------
// out = ua * (1 + softmax(ue @ W^T) @ W); W staged in LDS (broadcast reads)
template<bool F32>
__device__ __forceinline__ void gate_body(
    const void* usr, const float* w, float* usr_out, int u)
{
    float p[NRELM1];
    #pragma unroll
    for (int r = 0; r < NRELM1; ++r) p[r] = 0.f;
    #pragma unroll 4
    for (int t = 0; t < 16; ++t) {
        f4 ue = row4<F32>(usr, u, t);
        #pragma unroll
        for (int r = 0; r < NRELM1; ++r) {
            const float4 wv = *(const float4*)(w + r * DIM + 4 * t);
            p[r] += ue.x * wv.x + ue.y * wv.y + ue.z * wv.z + ue.w * wv.w;
        }
    }
    float mx = -1e30f;
    #pragma unroll
    for (int r = 0; r < NRELM1; ++r) mx = fmaxf(mx, p[r]);
    float sum = 0.f;
    #pragma unroll
    for (int r = 0; r < NRELM1; ++r) { p[r] = __expf(p[r] - mx); sum += p[r]; }
    float inv = 1.f / sum;
    #pragma unroll
    for (int r = 0; r < NRELM1; ++r) p[r] *= inv;

    float4* uo = (float4*)usr_out + (size_t)u * 16;
    #pragma unroll 4
    for (int t = 0; t < 16; ++t) {
        float gx = 0.f, gy = 0.f, gz = 0.f, gw = 0.f;
        #pragma unroll
        for (int r = 0; r < NRELM1; ++r) {
            const float4 wv = *(const float4*)(w + r * DIM + 4 * t);
            gx += p[r] * wv.x; gy += p[r] * wv.y; gz += p[r] * wv.z; gw += p[r] * wv.w;
        }
        float4 ua = uo[t];
        ua.x *= (1.f + gx); ua.y *= (1.f + gy); ua.z *= (1.f + gz); ua.w *= (1.f + gw);
        uo[t] = ua;
    }
}

__global__ __launch_bounds__(256) void gate_kernel(
    const void* __restrict__ usr, const void* __restrict__ wgt,
    float* __restrict__ usr_out, const int* __restrict__ flags)
{
    __shared__ float w[NRELM1 * DIM];
    int isf32 = flags[1];
    for (int i = threadIdx.x; i < NRELM1 * DIM; i += blockDim.x)
        w[i] = getf(wgt, i, isf32);
    __syncthreads();
    int u = blockIdx.x * blockDim.x + threadIdx.x;
    if (u >= N_USR) return;
    if (isf32) gate_body<true>(usr, w, usr_out, u);
    else       gate_body<false>(usr, w, usr_out, u);
}

extern "C" void kernel_launch(void* const* d_in, const int* in_sizes, int n_in,
                              void* d_out, int out_size, void* d_ws, size_t ws_size,
                              hipStream_t stream) {
    const void* ent  = d_in[0];
    const void* usr  = d_in[1];
    const int* eidx  = (const int*)d_in[2];
    const int* etype = (const int*)d_in[3];
    const int* irow  = (const int*)d_in[4];
    const int* icol  = (const int*)d_in[5];
    const void* ival = d_in[6];
    const void* wgt  = d_in[7];

    float* ent_out = (float*)d_out;                   // [N_ENT*DIM] fp32
    float* usr_out = ent_out + (size_t)N_ENT * DIM;   // [N_USR*DIM] fp32

    // workspace layout
    float* norm2 = (float*)d_ws;                           // N_ENT*32 (stride-32 rows)
    unsigned int* csr_e = (unsigned int*)(norm2 + (size_t)N_ENT * 32);  // NE+64
    uint2* uv   = (uint2*)(csr_e + NE + 64);               // NNZV (8B aligned)
    int* cnt    = (int*)(uv + NNZV);                       // NSEG
    int* loc    = cnt + NSEG;                              // NSEG
    int* btot   = loc + NSEG;                              // 256
    int* offs   = btot + 256;                              // NSEG
    int* cursor = offs + NSEG;                             // NSEG
    int* flags  = cursor + NSEG;                           // 2

    detect_kernel<<<1, 64, 0, stream>>>(eidx, (const unsigned short*)ent, flags);
    hipMemsetAsync(cnt, 0, (size_t)NSEG * sizeof(int), stream);

    hist_kernel<<<(NE + NNZV + 255) / 256, 256, 0, stream>>>(eidx, irow, cnt, flags);
    scan1_kernel<<<NB, SCAN_B, 0, stream>>>(cnt, loc, btot);
    scan2_kernel<<<1, 256, 0, stream>>>(btot);
    offs_kernel<<<(NSEG + 255) / 256, 256, 0, stream>>>(loc, btot, offs, cursor);
    scatter_kernel<<<((NE + NNZV + 255) / 256) * NXCD, 256, 0, stream>>>(
        eidx, etype, irow, icol, ival, cursor, csr_e, uv, flags);
    norm2_kernel<<<(N_ENT * DIM) / 256, 256, 0, stream>>>(ent, wgt, norm2, flags);
    agg_kernel<<<(N_ENT * DIM) / 256, 256, 0, stream>>>(
        ent, wgt, offs, cnt, csr_e, norm2, ent_out, flags);
    spmm_kernel<<<(N_USR * DIM) / 256, 256, 0, stream>>>(
        ent, offs, cnt, uv, usr_out, flags);
    gate_kernel<<<(N_USR + 255) / 256, 256, 0, stream>>>(usr, wgt, usr_out, flags);
}